// Round 2
// baseline (350.266 us; speedup 1.0000x reference)
//
#include <hip/hip_runtime.h>
#include <math.h>

typedef _Float16 f16;
typedef unsigned int u32;
typedef __attribute__((ext_vector_type(8))) f16 f16x8;
typedef __attribute__((ext_vector_type(4))) f16 f16x4;
typedef __attribute__((ext_vector_type(4))) float f32x4;
typedef __attribute__((ext_vector_type(16))) float f32x16;

#define DEV static __device__ __forceinline__

#define NB 2
#define SEQ 2048
#define DMODEL 1536
#define NHEADS 8
#define DQK 128
#define DVV 192
#define QKVW 1344              // 8*128 + 128 + 192
#define SCALEQK 0.08838834764831845f
#define LOG2E 1.4426950408889634f

// ---------------- workspace layout (bytes) ----------------
#define OFF_WQKVT 0ull                  // f16 [1344][1536]   4,128,768
#define OFF_WOUTT 4128768ull            // f16 [1536][1536]   4,718,592
#define OFF_QKV   8847360ull            // f32 [4096][1344]  22,020,096
#define OFF_Q     30867456ull           // f16 [2*8][2048][128] 8,388,608
#define OFF_K     39256064ull           // f16 [2][2048][128] 1,048,576
#define OFF_V     40304640ull           // f16 [2][2048][192] 1,572,864
#define OFF_VT    41877504ull           // f16 [2][192][2048] 1,572,864
#define OFF_VSUM  43450368ull           // f32 [256] sums     1,024
#define OFF_SG    43451392ull           // f32 sg[128], sb[128] 1,024
#define OFF_BIASC 43452416ull           // f32 [2][8][512][512] 16,777,216
#define OFF_AO    60229632ull           // f16 [2][2048][1536] 12,582,912
// total ~72.8 MB

DEV float fexp2(float x){
#if __has_builtin(__builtin_amdgcn_exp2f)
  return __builtin_amdgcn_exp2f(x);
#else
  return exp2f(x);
#endif
}
DEV float frcp(float x){
#if __has_builtin(__builtin_amdgcn_rcpf)
  return __builtin_amdgcn_rcpf(x);
#else
  return 1.0f/x;
#endif
}

typedef u32 __attribute__((address_space(1))) u32g;
typedef u32 __attribute__((address_space(3))) u32l;
DEV void g2l16(const void* g, void* l){
  // async global->LDS, 16B per lane; LDS dest = wave-uniform base + lane*16
  __builtin_amdgcn_global_load_lds((const u32g*)g, (u32l*)l, 16, 0, 0);
}

#define MFMA32(a,b,c) __builtin_amdgcn_mfma_f32_32x32x16_f16(a,b,c,0,0,0)
#define MFMA16(a,b,c) __builtin_amdgcn_mfma_f32_16x16x32_f16(a,b,c,0,0,0)

DEV f32x16 zero16(){
  f32x16 v;
  #pragma unroll
  for (int i=0;i<16;i++) v[i]=0.f;
  return v;
}
DEV f32x4 zero4(){
  f32x4 v;
  #pragma unroll
  for (int i=0;i<4;i++) v[i]=0.f;
  return v;
}
DEV float gelu_f(float x){ return 0.5f*x*(1.f + erff(x*0.70710678118654752440f)); }

// ---------------- transpose + f32->f16 convert for weights ----------------
__global__ void wtrans(const float* __restrict__ src, f16* __restrict__ dst, int K, int N){
  __shared__ float t[32][33];
  int k0 = blockIdx.x*32, n0 = blockIdx.y*32;
  int tx = threadIdx.x, ty = threadIdx.y;
  #pragma unroll
  for (int i=0;i<4;i++){ int r = ty+8*i; t[r][tx] = src[(size_t)(k0+r)*N + n0+tx]; }
  __syncthreads();
  #pragma unroll
  for (int i=0;i<4;i++){ int r = ty+8*i; dst[(size_t)(n0+r)*K + k0+tx] = (f16)t[tx][r]; }
}

// ---------------- QKV GEMM: qkv(f32) = x(4096x1536) @ w_qkv(1536x1344) ----------------
__global__ __launch_bounds__(256,2) void qkv_gemm(const float* __restrict__ X,
                                                  const f16* __restrict__ WT,
                                                  float* __restrict__ qkv){
  __shared__ char lds[49152]; // 2 x (A 16KB + B 8KB)
  int nb = blockIdx.x*64, mb = blockIdx.y*128;
  int tid = threadIdx.x;
  int w = tid>>6, lane = tid&63, li = lane&31, h = lane>>5;
  int arow = tid>>4, acq = tid&15;       // A staging: 16 float4 per row
  int brow = lane>>3, bc = lane&7;       // B staging: 8 rows per 1KB slot
  f32x16 acc[2]; acc[0]=zero16(); acc[1]=zero16();
  f32x4 ar[8];

#define QG_ISSUE_B(buf, kt_) do { \
    char* bd = lds + (buf)*24576 + 16384; \
    _Pragma("unroll") \
    for (int s=0;s<2;s++){ \
      int slot = w*2+s; int nl = slot*8 + brow; int cs = bc ^ (nl&7); \
      g2l16(WT + (size_t)(nb+nl)*DMODEL + (kt_)*64 + cs*8, bd + slot*1024); \
    } } while(0)
#define QG_LOAD_A(kt_) do { \
    _Pragma("unroll") \
    for (int i=0;i<8;i++) \
      ar[i] = *(const f32x4*)(X + (size_t)(mb + arow + 16*i)*DMODEL + (kt_)*64 + acq*4); \
    } while(0)
#define QG_WRITE_A(buf) do { \
    char* ad = lds + (buf)*24576; \
    _Pragma("unroll") \
    for (int i=0;i<8;i++){ \
      int rr = arow + 16*i; int ch = (acq>>1) ^ (rr&7); \
      f16x4 t4; t4[0]=(f16)ar[i][0]; t4[1]=(f16)ar[i][1]; t4[2]=(f16)ar[i][2]; t4[3]=(f16)ar[i][3]; \
      *(f16x4*)(ad + rr*128 + ch*16 + (acq&1)*8) = t4; \
    } } while(0)

  QG_ISSUE_B(0,0); QG_LOAD_A(0); QG_WRITE_A(0);
  __syncthreads();
  for (int kt=0; kt<24; kt++){
    int cur = kt&1;
    if (kt<23){ QG_ISSUE_B(cur^1, kt+1); QG_LOAD_A(kt+1); }
    const char* ad = lds + cur*24576;
    const char* bd = lds + cur*24576 + 16384;
    int ml = w*32 + li;
    #pragma unroll
    for (int ks=0; ks<4; ks++){
      f16x8 af = *(const f16x8*)(ad + ml*128 + (((2*ks+h) ^ (ml&7))*16));
      #pragma unroll
      for (int nf=0; nf<2; nf++){
        int nl = nf*32 + li;
        f16x8 bf = *(const f16x8*)(bd + nl*128 + (((2*ks+h) ^ (nl&7))*16));
        acc[nf] = MFMA32(af, bf, acc[nf]);
      }
    }
    if (kt<23) QG_WRITE_A(cur^1);
    __syncthreads();
  }
  #pragma unroll
  for (int nf=0; nf<2; nf++)
    #pragma unroll
    for (int r=0;r<16;r++){
      int m = mb + w*32 + (r&3) + 8*(r>>2) + 4*h;
      int n = nb + nf*32 + li;
      qkv[(size_t)m*QKVW + n] = acc[nf][r];
    }
#undef QG_ISSUE_B
#undef QG_LOAD_A
#undef QG_WRITE_A
}

// ---------------- LayerNorm + f16 pack: qkv -> Q,K,V ----------------
__global__ __launch_bounds__(64) void ln_pack(const float* __restrict__ qkv,
    const float* __restrict__ qw, const float* __restrict__ qb,
    const float* __restrict__ kw, const float* __restrict__ kb,
    const float* __restrict__ vw, const float* __restrict__ vb,
    f16* __restrict__ Q, f16* __restrict__ K, f16* __restrict__ V){
  int bid = blockIdx.x;
  int row = bid / 10, seg = bid - row*10;   // 10 segments: 8 q-heads, k, v
  int b = row >> 11, n = row & 2047;
  int lane = threadIdx.x;
  const float* base = qkv + (size_t)row*QKVW;
  if (seg < 9){
    int off = seg*128;  // seg==8 -> 1024 (k)
    float x0 = base[off+lane], x1 = base[off+64+lane];
    float s = x0+x1;
    #pragma unroll
    for (int d=32; d>=1; d>>=1) s += __shfl_xor(s, d);
    float mu = s*(1.f/128.f);
    float d0 = x0-mu, d1 = x1-mu;
    float vv = d0*d0 + d1*d1;
    #pragma unroll
    for (int d=32; d>=1; d>>=1) vv += __shfl_xor(vv, d);
    float istd = rsqrtf(vv*(1.f/128.f) + 1e-5f);
    const float* W  = (seg<8)? qw : kw;
    const float* Bi = (seg<8)? qb : kb;
    f16* dst = (seg<8) ? (Q + ((size_t)(b*NHEADS+seg)*SEQ + n)*DQK)
                       : (K + ((size_t)(b*SEQ+n))*DQK);
    dst[lane]    = (f16)(d0*istd*W[lane] + Bi[lane]);
    dst[lane+64] = (f16)(d1*istd*W[lane+64] + Bi[lane+64]);
  } else {
    float x0 = base[1152+lane], x1 = base[1152+64+lane], x2 = base[1152+128+lane];
    float s = x0+x1+x2;
    #pragma unroll
    for (int d=32; d>=1; d>>=1) s += __shfl_xor(s, d);
    float mu = s*(1.f/192.f);
    float d0=x0-mu, d1=x1-mu, d2=x2-mu;
    float vv = d0*d0+d1*d1+d2*d2;
    #pragma unroll
    for (int d=32; d>=1; d>>=1) vv += __shfl_xor(vv, d);
    float istd = rsqrtf(vv*(1.f/192.f) + 1e-5f);
    f16* dst = V + (size_t)(b*SEQ+n)*DVV;
    dst[lane]     = (f16)(d0*istd*vw[lane] + vb[lane]);
    dst[lane+64]  = (f16)(d1*istd*vw[lane+64] + vb[lane+64]);
    dst[lane+128] = (f16)(d2*istd*vw[lane+128] + vb[lane+128]);
  }
}

// ---------------- V transpose: (b,2048,192) -> (b,192,2048) ----------------
__global__ void vtrans(const f16* __restrict__ V, f16* __restrict__ VT){
  __shared__ f16 t[32][33];
  int b = blockIdx.z; int d0 = blockIdx.x*32; int j0 = blockIdx.y*32;
  int tx = threadIdx.x, ty = threadIdx.y;
  #pragma unroll
  for (int i=0;i<4;i++){ int r = ty+8*i; t[r][tx] = V[((size_t)b*SEQ + j0+r)*DVV + d0+tx]; }
  __syncthreads();
  #pragma unroll
  for (int i=0;i<4;i++){ int r = ty+8*i; VT[((size_t)b*DVV + d0+r)*SEQ + j0+tx] = t[tx][r]; }
}

// ---------------- pairwise per-channel sum/sumsq ----------------
__global__ __launch_bounds__(256,4) void pvar(const float* __restrict__ pw, float* __restrict__ sums){
  int tid = threadIdx.x;
  int c = tid & 127, hh = tid >> 7;
  float s1 = 0.f, s2 = 0.f;
  const float* p0 = pw + ((size_t)blockIdx.x*512 + hh)*128 + c;
  #pragma unroll 4
  for (int it=0; it<256; it++){
    float v = p0[(size_t)it*256];
    s1 += v; s2 += v*v;
  }
  __shared__ float r1[256], r2[256];
  r1[tid] = s1; r2[tid] = s2;
  __syncthreads();
  if (tid < 128){
    atomicAdd(&sums[c],     r1[tid] + r1[tid+128]);
    atomicAdd(&sums[128+c], r2[tid] + r2[tid+128]);
  }
}

__global__ void finvar(const float* __restrict__ sums, const float* __restrict__ rvar,
                       const float* __restrict__ gamma, const float* __restrict__ beta,
                       float* __restrict__ sg, float* __restrict__ sb){
  int c = threadIdx.x;
  const float Minv = 1.f/524288.f;
  float m = sums[c]*Minv;
  float var = sums[128+c]*Minv - m*m;
  float rv = rvar[c]*0.9f + 0.1f*var;
  float istd = rsqrtf(rv + 1e-5f);
  sg[c] = istd*gamma[c];
  sb[c] = beta[c];
}

// ---------------- bias = gelu(norm(pairwise)) @ w_bias -> (b,8,512,512) f32 ----------------
__global__ __launch_bounds__(256,2) void bias_gemm(const float* __restrict__ pw,
    const float* __restrict__ sg, const float* __restrict__ sb,
    const float* __restrict__ wb, float* __restrict__ biasc){
  int tid = threadIdx.x;
  int w = tid>>6, lane = tid&63;
  int il = lane&15, kg = lane>>4;
  f16x8 bw[4];
  float sgr[32], sbr[32];
  #pragma unroll
  for (int t=0;t<4;t++)
    #pragma unroll
    for (int e=0;e<8;e++){
      int k = t*32 + kg*8 + e;
      bw[t][e] = (f16)((il<8) ? wb[k*8 + il] : 0.f);
      sgr[t*8+e] = sg[k];
      sbr[t*8+e] = sb[k];
    }
  for (int it=0; it<8; it++){
    int tile = blockIdx.x*4 + w + it*4096;   // 32768 row-tiles of 16
    size_t rg = (size_t)tile*16 + il;
    f32x4 acc = zero4();
    #pragma unroll
    for (int t=0;t<4;t++){
      const float* sp = pw + rg*128 + t*32 + kg*8;
      f32x4 v0 = *(const f32x4*)sp;
      f32x4 v1 = *(const f32x4*)(sp+4);
      f16x8 af;
      #pragma unroll
      for (int e=0;e<4;e++) af[e]   = (f16)gelu_f(v0[e]*sgr[t*8+e]   + sbr[t*8+e]);
      #pragma unroll
      for (int e=0;e<4;e++) af[4+e] = (f16)gelu_f(v1[e]*sgr[t*8+4+e] + sbr[t*8+4+e]);
      acc = MFMA16(af, bw[t], acc);
    }
    if (il < 8){
      #pragma unroll
      for (int r=0;r<4;r++){
        size_t rr = (size_t)tile*16 + kg*4 + r;
        int bb = (int)(rr >> 18);
        int rem = (int)(rr & 262143);
        int ii = rem >> 9, jj = rem & 511;
        biasc[(((size_t)(bb*8 + il)*512) + ii)*512 + jj] = acc[r];
      }
    }
  }
}

// ---------------- fused attention ----------------
// grid 256: bid = qt*16 + bg (keeps one (b,g)'s 16 q-tiles on one XCD)
__global__ __launch_bounds__(256,1) void attn(const f16* __restrict__ Q, const f16* __restrict__ K,
                                              const f16* __restrict__ VT, const float* __restrict__ biasc,
                                              f16* __restrict__ AO){
  __shared__ char lds[81920];      // 2 x (K 16KB + VT 24KB)
  __shared__ float linvb[4][32];
  int bid = blockIdx.x;
  int bg = bid & 15, qt = bid >> 4;
  int b = bg >> 3, g = bg & 7;
  int tid = threadIdx.x;
  int w = tid >> 6, lane = tid & 63;
  int li = lane & 31, h = lane >> 5;

  const f16* Qb = Q  + (size_t)bg*SEQ*DQK;
  const f16* Kb = K  + (size_t)b*SEQ*DQK;
  const f16* Vb = VT + (size_t)b*DVV*SEQ;

  int qrow = qt*128 + w*32 + li;
  f16x8 qf[8];
  #pragma unroll
  for (int ks=0; ks<8; ks++)
    qf[ks] = *(const f16x8*)(Qb + (size_t)qrow*DQK + ks*16 + h*8);

  const float* brow = biasc + ((size_t)bg*512 + (qrow>>2))*512;

  f32x16 oacc[6];
  #pragma unroll
  for (int nf=0;nf<6;nf++) oacc[nf] = zero16();
  float lsum = 0.f;

  int kl_row = lane >> 4, kl_c = lane & 15;  // K tile: 4 rows/KB slot (256B rows)
  int vl_row = lane >> 3, vl_c = lane & 7;   // VT tile: 8 rows/KB slot (128B rows)

#define STAGE(buf, jt_) do { \
    char* kd = lds + (buf)*40960; \
    const f16* ksrc = Kb + (size_t)(jt_)*64*DQK; \
    _Pragma("unroll") \
    for (int s=0;s<4;s++){ \
      int slot = w*4+s; int jr = slot*4 + kl_row; int cs = kl_c ^ (jr&7); \
      g2l16(ksrc + (size_t)jr*DQK + cs*8, kd + slot*1024); \
    } \
    char* vd = lds + (buf)*40960 + 16384; \
    _Pragma("unroll") \
    for (int s=0;s<6;s++){ \
      int slot = w*6+s; int dvr = slot*8 + vl_row; int cs = vl_c ^ (dvr&7); \
      g2l16(Vb + (size_t)dvr*SEQ + (size_t)(jt_)*64 + cs*8, vd + slot*1024); \
    } } while(0)

  STAGE(0, 0);

  const float CS = SCALEQK * (2.f*LOG2E/5.f);
  const float CB = 2.f*LOG2E/5.f;
  const float CP = 5.f*LOG2E;

  for (int jt=0; jt<32; jt++){
    int cur = jt & 1;
    __syncthreads();                       // stage(jt) landed (vmcnt drain at barrier)
    if (jt < 31) STAGE(cur^1, jt+1);       // async prefetch of next tile
    const char* kb_ = lds + cur*40960;
    const char* vb_ = lds + cur*40960 + 16384;
    #pragma unroll
    for (int sub=0; sub<2; sub++){
      // S^T = K_tile @ Q^T  (lane li owns q-row li; regs r -> j = (r&3)+8*(r>>2)+4h)
      f32x16 sacc = zero16();
      int jr = sub*32 + li;
      #pragma unroll
      for (int ks=0; ks<8; ks++){
        int ck = (2*ks + h) ^ (jr&7);
        f16x8 kf = *(const f16x8*)(kb_ + jr*256 + ck*16);
        sacc = MFMA32(kf, qf[ks], sacc);
      }
      int jb4 = jt*16 + sub*8;
      float bt[4];
      #pragma unroll
      for (int q=0;q<4;q++) bt[q] = brow[jb4 + 2*q + h] * CB;
      // softclamp + exp (no online max: logits bounded to (-5,5))
      float p[16], xp[16];
      #pragma unroll
      for (int r=0;r<16;r++){
        float u2 = sacc[r]*CS + bt[r>>2];
        float E  = fexp2(u2);                  // e^{2u}; inf-safe
        float tn = 1.f - 2.f*frcp(E + 1.f);    // tanh(u)
        float pr = fexp2(tn * CP);             // e^{5*tanh(u)}
        p[r] = pr;
        lsum += pr;
      }
      #pragma unroll
      for (int r=0;r<16;r++) xp[r] = __shfl_xor(p[r], 32);
      #pragma unroll
      for (int ks2=0; ks2<2; ks2++){
        f16x8 pa;
        #pragma unroll
        for (int e=0;e<4;e++) pa[e] = (f16)(h ? xp[8*ks2+4+e] : p[8*ks2+e]);
        #pragma unroll
        for (int e=4;e<8;e++) pa[e] = (f16)(h ? p[8*ks2+e]    : xp[8*ks2+e-4]);
        #pragma unroll
        for (int nf=0; nf<6; nf++){
          int dvr = nf*32 + li;
          int cj = (sub*4 + 2*ks2 + h) ^ (dvr&7);
          f16x8 vf = *(const f16x8*)(vb_ + dvr*128 + cj*16);
          oacc[nf] = MFMA32(pa, vf, oacc[nf]);
        }
      }
    }
  }
  float ltot = lsum + __shfl_xor(lsum, 32);
  float linv = 1.f / ltot;
  if (h == 0) linvb[w][li] = linv;
  __syncthreads();
  #pragma unroll
  for (int nf=0; nf<6; nf++)
    #pragma unroll
    for (int r=0;r<16;r++){
      int il = (r&3) + 8*(r>>2) + 4*h;
      float ov = oacc[nf][r] * linvb[w][il];
      int orow = qt*128 + w*32 + il;
      AO[((size_t)(b*SEQ + orow)*NHEADS + g)*DVV + nf*32 + li] = (f16)ov;
    }
#undef STAGE
}

// ---------------- out GEMM: out = AO(4096x1536 f16) @ w_out + b_out (f32) ----------------
__global__ __launch_bounds__(256,2) void out_gemm(const f16* __restrict__ A, const f16* __restrict__ WT,
                                                  const float* __restrict__ bo, float* __restrict__ out){
  __shared__ char lds[49152];
  int nb = blockIdx.x*64, mb = blockIdx.y*128;
  int tid = threadIdx.x;
  int w = tid>>6, lane = tid&63, li = lane&31, h = lane>>5;
  int srow = lane>>3, sc = lane&7;
  f32x16 acc[2]; acc[0]=zero16(); acc[1]=zero16();

#define OG_STAGE(buf, kt_) do { \
    char* ad = lds + (buf)*24576; \
    _Pragma("unroll") \
    for (int s=0;s<4;s++){ \
      int slot = w*4+s; int mlr = slot*8 + srow; int cs = sc ^ (mlr&7); \
      g2l16(A + (size_t)(mb+mlr)*DMODEL + (kt_)*64 + cs*8, ad + slot*1024); \
    } \
    char* bd = lds + (buf)*24576 + 16384; \
    _Pragma("unroll") \
    for (int s=0;s<2;s++){ \
      int slot = w*2+s; int nl = slot*8 + srow; int cs = sc ^ (nl&7); \
      g2l16(WT + (size_t)(nb+nl)*DMODEL + (kt_)*64 + cs*8, bd + slot*1024); \
    } } while(0)

  OG_STAGE(0,0);
  __syncthreads();
  for (int kt=0; kt<24; kt++){
    int cur = kt&1;
    if (kt<23) OG_STAGE(cur^1, kt+1);
    const char* ad = lds + cur*24576;
    const char* bd = lds + cur*24576 + 16384;
    int ml = w*32 + li;
    #pragma unroll
    for (int ks=0; ks<4; ks++){
      f16x8 af = *(const f16x8*)(ad + ml*128 + (((2*ks+h) ^ (ml&7))*16));
      #pragma unroll
      for (int nf=0; nf<2; nf++){
        int nl = nf*32 + li;
        f16x8 bf = *(const f16x8*)(bd + nl*128 + (((2*ks+h) ^ (nl&7))*16));
        acc[nf] = MFMA32(af, bf, acc[nf]);
      }
    }
    __syncthreads();
  }
  float bo0 = bo[nb+li], bo1 = bo[nb+32+li];
  #pragma unroll
  for (int nf=0; nf<2; nf++)
    #pragma unroll
    for (int r=0;r<16;r++){
      int m = mb + w*32 + (r&3) + 8*(r>>2) + 4*h;
      int n = nb + nf*32 + li;
      out[(size_t)m*DMODEL + n] = acc[nf][r] + (nf ? bo1 : bo0);
    }
#undef OG_STAGE
}

extern "C" void kernel_launch(void* const* d_in, const int* in_sizes, int n_in,
                              void* d_out, int out_size, void* d_ws, size_t ws_size,
                              hipStream_t stream) {
  (void)in_sizes; (void)n_in; (void)out_size; (void)ws_size;
  const float* x        = (const float*)d_in[0];
  const float* pairwise = (const float*)d_in[1];
  const float* w_qkv    = (const float*)d_in[2];
  const float* q_w      = (const float*)d_in[3];
  const float* q_b      = (const float*)d_in[4];
  const float* k_w      = (const float*)d_in[5];
  const float* k_b      = (const float*)d_in[6];
  const float* v_w      = (const float*)d_in[7];
  const float* v_b      = (const float*)d_in[8];
  const float* bgamma   = (const float*)d_in[9];
  const float* bbeta    = (const float*)d_in[10];
  const float* brvar    = (const float*)d_in[11];
  const float* w_bias   = (const float*)d_in[12];
  const float* w_out    = (const float*)d_in[13];
  const float* b_out    = (const float*)d_in[14];
  float* out = (float*)d_out;

  char* ws = (char*)d_ws;
  f16*   wqkvT = (f16*)(ws + OFF_WQKVT);
  f16*   woutT = (f16*)(ws + OFF_WOUTT);
  float* qkvb  = (float*)(ws + OFF_QKV);
  f16*   Qh    = (f16*)(ws + OFF_Q);
  f16*   Kh    = (f16*)(ws + OFF_K);
  f16*   Vh    = (f16*)(ws + OFF_V);
  f16*   VTh   = (f16*)(ws + OFF_VT);
  float* vsum  = (float*)(ws + OFF_VSUM);
  float* sg    = (float*)(ws + OFF_SG);
  float* sb    = sg + 128;
  float* biasc = (float*)(ws + OFF_BIASC);
  f16*   AOh   = (f16*)(ws + OFF_AO);

  (void)hipMemsetAsync(ws + OFF_VSUM, 0, 1024, stream);
  wtrans<<<dim3(48,42), dim3(32,8), 0, stream>>>(w_qkv, wqkvT, 1536, 1344);
  wtrans<<<dim3(48,48), dim3(32,8), 0, stream>>>(w_out, woutT, 1536, 1536);
  qkv_gemm<<<dim3(21,32), 256, 0, stream>>>(x, wqkvT, qkvb);
  ln_pack<<<40960, 64, 0, stream>>>(qkvb, q_w,q_b,k_w,k_b,v_w,v_b, Qh, Kh, Vh);
  vtrans<<<dim3(6,64,2), dim3(32,8), 0, stream>>>(Vh, VTh);
  pvar<<<1024, 256, 0, stream>>>(pairwise, vsum);
  finvar<<<1, 128, 0, stream>>>(vsum, brvar, bgamma, bbeta, sg, sb);
  bias_gemm<<<1024, 256, 0, stream>>>(pairwise, sg, sb, w_bias, biasc);
  attn<<<256, 256, 0, stream>>>(Qh, Kh, VTh, biasc, AOh);
  out_gemm<<<dim3(24,32), 256, 0, stream>>>(AOh, woutT, b_out, out);
}